// Round 5
// baseline (334.086 us; speedup 1.0000x reference)
//
#include <hip/hip_runtime.h>
#include <hip/hip_bf16.h>
#include <math.h>

#define NN 20000
#define NE 320000

#define NB 256   // blocks in build_csr (<= 256 CUs -> all co-resident)
#define BT 256   // threads per block
#define CH 80    // scan chunk per block
#define NSB 250  // active scan blocks (250*80 = 20000)

typedef __attribute__((ext_vector_type(8))) short bf16x8;
typedef __attribute__((ext_vector_type(4))) float f32x4;

__device__ inline float bf2f_lo(uint v) {
    union { uint i; float f; } c; c.i = v << 16; return c.f;
}
__device__ inline float bf2f_hi(uint v) {
    union { uint i; float f; } c; c.i = v & 0xffff0000u; return c.f;
}
__device__ inline ushort f2bf(float f) {
    __hip_bfloat16 h = __float2bfloat16(f);
    return *reinterpret_cast<ushort*>(&h);
}

// device-scope grid barrier; generation-counted (cnt never resets, rel monotone).
// Safe because grid = 256 blocks of 256 threads -> all blocks co-resident.
__device__ inline void grid_sync(int* cnt, int* rel, int gen) {
    __syncthreads();
    if (threadIdx.x == 0) {
        __threadfence();  // release prior writes to device scope
        int old = atomicAdd(cnt, 1);
        if (old == gen * NB - 1)
            __hip_atomic_store(rel, gen, __ATOMIC_RELEASE, __HIP_MEMORY_SCOPE_AGENT);
        while (__hip_atomic_load(rel, __ATOMIC_ACQUIRE, __HIP_MEMORY_SCOPE_AGENT) < gen)
            __builtin_amdgcn_s_sleep(2);
    }
    __syncthreads();
}

// -------- fused CSR build: zero -> count -> 2-level scan -> offsets/cursor -> fill1 --------
__global__ __launch_bounds__(BT) void build_csr(const int* __restrict__ dst,
                                                int* __restrict__ counts,
                                                int* __restrict__ offsets,
                                                int* __restrict__ cursor,
                                                int* __restrict__ csr_eidx,
                                                int* __restrict__ blockSums,
                                                int* __restrict__ blockBase,
                                                int* bar_cnt, int* bar_rel) {
    int b = blockIdx.x, t = threadIdx.x;
    int gt = b * BT + t;
    // P0: zero counts
    for (int i = gt; i < NN; i += NB * BT) counts[i] = 0;
    grid_sync(bar_cnt, bar_rel, 1);
    // P1: count (atomics resolve at L2, device scope)
    for (int e = gt; e < NE; e += NB * BT) atomicAdd(&counts[dst[e]], 1);
    grid_sync(bar_cnt, bar_rel, 2);
    // P2a: per-block local scan of CH elems (agent loads: bypass possibly-stale L1)
    __shared__ int s[BT];
    int idx = b * CH + t;
    int myv = 0;
    if (b < NSB && t < CH)
        myv = __hip_atomic_load(&counts[idx], __ATOMIC_RELAXED, __HIP_MEMORY_SCOPE_AGENT);
    s[t] = myv;
    __syncthreads();
    for (int off = 1; off < BT; off <<= 1) {
        int add = (t >= off) ? s[t - off] : 0;
        __syncthreads();
        s[t] += add;
        __syncthreads();
    }
    int ex = s[t] - myv;  // exclusive prefix within block
    if (b < NSB && t == 0) blockSums[b] = s[CH - 1];
    grid_sync(bar_cnt, bar_rel, 3);
    // P2b: block 0 scans the 250 block sums
    if (b == 0) {
        int v2 = (t < NSB) ? __hip_atomic_load(&blockSums[t], __ATOMIC_RELAXED,
                                               __HIP_MEMORY_SCOPE_AGENT)
                           : 0;
        s[t] = v2;
        __syncthreads();
        for (int off = 1; off < BT; off <<= 1) {
            int add = (t >= off) ? s[t - off] : 0;
            __syncthreads();
            s[t] += add;
            __syncthreads();
        }
        if (t < NSB) blockBase[t] = s[t] - v2;
    }
    grid_sync(bar_cnt, bar_rel, 4);
    // P2c: final offsets + cursor
    if (b < NSB && t < CH) {
        int base = __hip_atomic_load(&blockBase[b], __ATOMIC_RELAXED, __HIP_MEMORY_SCOPE_AGENT);
        int o = base + ex;
        offsets[idx] = o;
        cursor[idx] = o;
    }
    if (gt == 0) offsets[NN] = NE;
    grid_sync(bar_cnt, bar_rel, 5);
    // P3: fill1 — scatter 4B edge index into CSR order
    for (int e = gt; e < NE; e += NB * BT) {
        int pos = atomicAdd(&cursor[dst[e]], 1);
        csr_eidx[pos] = e;
    }
}

struct EdgeParams {
    const float *pw0, *pb0, *mu0, *is0;
    const float *pw1, *pb1, *mu1, *is1;
    const float *pw2, *pb2, *mu2, *is2;
};

__device__ inline float fast_tanh(float x) {
    x = fminf(fmaxf(x, -9.f), 9.f);
    float e = __expf(2.f * x);
    return 1.f - 2.f / (e + 1.f);
}

__device__ inline void layer_w(float p0, float p1, const float* pw, const float* pb,
                               const float* mu, const float* is, float* out4) {
    float u0 = fast_tanh(p0 * pw[0] + p1 * pw[2] + pb[0]);
    float u1 = fast_tanh(p0 * pw[1] + p1 * pw[3] + pb[1]);
#pragma unroll
    for (int k = 0; k < 4; ++k) {
        float d0 = (u0 - mu[k * 2 + 0]) * is[k * 2 + 0];
        float d1 = (u1 - mu[k * 2 + 1]) * is[k * 2 + 1];
        out4[k] = __expf(-0.5f * (d0 * d0 + d1 * d1));
    }
}

// -------- fused: fill2 (blocks 0..1249) + weight transpose (blocks 1250..1889) --------
__global__ void fill2_prep(const int* __restrict__ csr_eidx, const int* __restrict__ src,
                           const float* __restrict__ pseudo, EdgeParams P,
                           int* __restrict__ csr_src, float* __restrict__ csr_w,
                           const float* __restrict__ f0, const float* __restrict__ f1,
                           const float* __restrict__ f2, ushort* __restrict__ w0,
                           ushort* __restrict__ w1, ushort* __restrict__ w2) {
    int bid = blockIdx.x;
    if (bid < 1250) {
        int i = bid * 256 + threadIdx.x;  // 1250*256 == NE exactly
        int e = csr_eidx[i];
        float2 p = *(const float2*)(pseudo + (size_t)e * 2);
        csr_src[i] = src[e];
        float w[4];
        layer_w(p.x, p.y, P.pw0, P.pb0, P.mu0, P.is0, w);
        *(float4*)(csr_w + (size_t)(0 * NE + i) * 4) = make_float4(w[0], w[1], w[2], w[3]);
        layer_w(p.x, p.y, P.pw1, P.pb1, P.mu1, P.is1, w);
        *(float4*)(csr_w + (size_t)(1 * NE + i) * 4) = make_float4(w[0], w[1], w[2], w[3]);
        layer_w(p.x, p.y, P.pw2, P.pb2, P.mu2, P.is2, w);
        *(float4*)(csr_w + (size_t)(2 * NE + i) * 4) = make_float4(w[0], w[1], w[2], w[3]);
    } else {
        int idx = (bid - 1250) * 256 + threadIdx.x;  // 640 blocks cover 163840 exactly
        const float* srcp;
        ushort* dstp;
        int din, KD, li;
        if (idx < 128 * 256) {
            srcp = f0; dstp = w0; din = 64; KD = 256; li = idx;
        } else if (idx < 128 * 256 + 128 * 512) {
            srcp = f1; dstp = w1; din = 128; KD = 512; li = idx - 128 * 256;
        } else {
            srcp = f2; dstp = w2; din = 128; KD = 512; li = idx - 128 * 256 - 128 * 512;
        }
        int n = li / KD;
        int r = li - n * KD;
        int k = r / din;
        int d = r - k * din;
        dstp[li] = f2bf(srcp[d * 512 + k * 128 + n]);
    }
}

// ---------------- layer-0 aggregation (fp32 features) -> bf16 t[n][k*64+d] ----------------
__global__ __launch_bounds__(64) void agg_f32_64(const float* __restrict__ h,
                                                 const int* __restrict__ offsets,
                                                 const int* __restrict__ csr_src,
                                                 const float* __restrict__ csr_w,
                                                 ushort* __restrict__ t) {
    int n = blockIdx.x;
    int lane = threadIdx.x;
    int b = offsets[n], eN = offsets[n + 1];
    float acc[4] = {0.f, 0.f, 0.f, 0.f};
    int i = b;
    for (; i + 4 <= eN; i += 4) {
        int s0 = csr_src[i], s1 = csr_src[i + 1], s2 = csr_src[i + 2], s3 = csr_src[i + 3];
        float4 w0 = *(const float4*)(csr_w + (size_t)i * 4);
        float4 w1 = *(const float4*)(csr_w + (size_t)(i + 1) * 4);
        float4 w2 = *(const float4*)(csr_w + (size_t)(i + 2) * 4);
        float4 w3 = *(const float4*)(csr_w + (size_t)(i + 3) * 4);
        float hv0 = h[(size_t)s0 * 64 + lane];
        float hv1 = h[(size_t)s1 * 64 + lane];
        float hv2 = h[(size_t)s2 * 64 + lane];
        float hv3 = h[(size_t)s3 * 64 + lane];
        acc[0] += w0.x * hv0 + w1.x * hv1 + w2.x * hv2 + w3.x * hv3;
        acc[1] += w0.y * hv0 + w1.y * hv1 + w2.y * hv2 + w3.y * hv3;
        acc[2] += w0.z * hv0 + w1.z * hv1 + w2.z * hv2 + w3.z * hv3;
        acc[3] += w0.w * hv0 + w1.w * hv1 + w2.w * hv2 + w3.w * hv3;
    }
    for (; i < eN; ++i) {
        int s0 = csr_src[i];
        float4 w0 = *(const float4*)(csr_w + (size_t)i * 4);
        float hv0 = h[(size_t)s0 * 64 + lane];
        acc[0] += w0.x * hv0;
        acc[1] += w0.y * hv0;
        acc[2] += w0.z * hv0;
        acc[3] += w0.w * hv0;
    }
#pragma unroll
    for (int k = 0; k < 4; ++k) t[(size_t)n * 256 + k * 64 + lane] = f2bf(acc[k]);
}

// ---------------- layer-1/2 aggregation (bf16 h, packed uint loads) -> bf16 t ----------------
__global__ __launch_bounds__(64) void agg_bf_128(const ushort* __restrict__ h,
                                                 const int* __restrict__ offsets,
                                                 const int* __restrict__ csr_src,
                                                 const float* __restrict__ csr_w,
                                                 ushort* __restrict__ t) {
    int n = blockIdx.x;
    int lane = threadIdx.x;
    int b = offsets[n], eN = offsets[n + 1];
    float acc[4][2];
#pragma unroll
    for (int k = 0; k < 4; ++k) { acc[k][0] = 0.f; acc[k][1] = 0.f; }
    int i = b;
    for (; i + 4 <= eN; i += 4) {
        int s0 = csr_src[i], s1 = csr_src[i + 1], s2 = csr_src[i + 2], s3 = csr_src[i + 3];
        float4 w0 = *(const float4*)(csr_w + (size_t)i * 4);
        float4 w1 = *(const float4*)(csr_w + (size_t)(i + 1) * 4);
        float4 w2 = *(const float4*)(csr_w + (size_t)(i + 2) * 4);
        float4 w3 = *(const float4*)(csr_w + (size_t)(i + 3) * 4);
        uint v0 = *(const uint*)(h + (size_t)s0 * 128 + lane * 2);
        uint v1 = *(const uint*)(h + (size_t)s1 * 128 + lane * 2);
        uint v2 = *(const uint*)(h + (size_t)s2 * 128 + lane * 2);
        uint v3 = *(const uint*)(h + (size_t)s3 * 128 + lane * 2);
        float a0 = bf2f_lo(v0), a1 = bf2f_hi(v0);
        float b0 = bf2f_lo(v1), b1 = bf2f_hi(v1);
        float c0 = bf2f_lo(v2), c1 = bf2f_hi(v2);
        float d0 = bf2f_lo(v3), d1 = bf2f_hi(v3);
        acc[0][0] += w0.x * a0 + w1.x * b0 + w2.x * c0 + w3.x * d0;
        acc[0][1] += w0.x * a1 + w1.x * b1 + w2.x * c1 + w3.x * d1;
        acc[1][0] += w0.y * a0 + w1.y * b0 + w2.y * c0 + w3.y * d0;
        acc[1][1] += w0.y * a1 + w1.y * b1 + w2.y * c1 + w3.y * d1;
        acc[2][0] += w0.z * a0 + w1.z * b0 + w2.z * c0 + w3.z * d0;
        acc[2][1] += w0.z * a1 + w1.z * b1 + w2.z * c1 + w3.z * d1;
        acc[3][0] += w0.w * a0 + w1.w * b0 + w2.w * c0 + w3.w * d0;
        acc[3][1] += w0.w * a1 + w1.w * b1 + w2.w * c1 + w3.w * d1;
    }
    for (; i < eN; ++i) {
        int s0 = csr_src[i];
        float4 w0 = *(const float4*)(csr_w + (size_t)i * 4);
        uint v0 = *(const uint*)(h + (size_t)s0 * 128 + lane * 2);
        float a0 = bf2f_lo(v0), a1 = bf2f_hi(v0);
        acc[0][0] += w0.x * a0; acc[0][1] += w0.x * a1;
        acc[1][0] += w0.y * a0; acc[1][1] += w0.y * a1;
        acc[2][0] += w0.z * a0; acc[2][1] += w0.z * a1;
        acc[3][0] += w0.w * a0; acc[3][1] += w0.w * a1;
    }
#pragma unroll
    for (int k = 0; k < 4; ++k) {
        ushort2 p;
        p.x = f2bf(acc[k][0]);
        p.y = f2bf(acc[k][1]);
        *(ushort2*)(t + (size_t)n * 512 + k * 128 + lane * 2) = p;
    }
}

// ---------------- bf16 MFMA GEMM: C[M][128] = A[M][KD] @ Bt[128][KD]^T + bias ----------------
template <int KD, bool OUTBF>
__global__ __launch_bounds__(128) void mfma_gemm(const ushort* __restrict__ A,
                                                 const ushort* __restrict__ Bt,
                                                 const float* __restrict__ bias,
                                                 void* __restrict__ Cout, int M) {
    constexpr int PITCH = 40;  // 32 + 8 ushorts: 80 B rows, 16B-aligned, 2-way banks only
    __shared__ __align__(16) ushort As[64 * PITCH];
    __shared__ __align__(16) ushort Bs[128 * PITCH];
    int tid = threadIdx.x;
    int wave = tid >> 6, lane = tid & 63;
    int quad = lane >> 4, l16 = lane & 15;
    int m0 = blockIdx.x * 64;

    f32x4 acc[4][4];
#pragma unroll
    for (int r = 0; r < 4; ++r)
#pragma unroll
        for (int c = 0; c < 4; ++c) acc[r][c] = (f32x4){0.f, 0.f, 0.f, 0.f};

    for (int k0 = 0; k0 < KD; k0 += 32) {
#pragma unroll
        for (int it = 0; it < 2; ++it) {
            int chunk = it * 128 + tid;
            int row = chunk >> 2, off = chunk & 3;
            int gm = m0 + row;
            uint4 v = make_uint4(0u, 0u, 0u, 0u);
            if (gm < M) v = *(const uint4*)(A + (size_t)gm * KD + k0 + off * 8);
            *(uint4*)(As + row * PITCH + off * 8) = v;
        }
#pragma unroll
        for (int it = 0; it < 4; ++it) {
            int chunk = it * 128 + tid;
            int nr = chunk >> 2, off = chunk & 3;
            uint4 v = *(const uint4*)(Bt + (size_t)nr * KD + k0 + off * 8);
            *(uint4*)(Bs + nr * PITCH + off * 8) = v;
        }
        __syncthreads();

        bf16x8 afrag[4], bfrag[4];
#pragma unroll
        for (int r = 0; r < 4; ++r)
            afrag[r] = *(const bf16x8*)(As + (r * 16 + l16) * PITCH + quad * 8);
#pragma unroll
        for (int c = 0; c < 4; ++c)
            bfrag[c] = *(const bf16x8*)(Bs + (wave * 64 + c * 16 + l16) * PITCH + quad * 8);
#pragma unroll
        for (int r = 0; r < 4; ++r)
#pragma unroll
            for (int c = 0; c < 4; ++c)
                acc[r][c] = __builtin_amdgcn_mfma_f32_16x16x32_bf16(afrag[r], bfrag[c],
                                                                    acc[r][c], 0, 0, 0);
        __syncthreads();
    }

#pragma unroll
    for (int c = 0; c < 4; ++c) {
        int gn = wave * 64 + c * 16 + l16;
        float bv = bias[gn];
#pragma unroll
        for (int r = 0; r < 4; ++r) {
            int gmb = m0 + r * 16 + quad * 4;
#pragma unroll
            for (int i = 0; i < 4; ++i) {
                int gm = gmb + i;
                if (gm < M) {
                    float val = acc[r][c][i] + bv;
                    if (OUTBF)
                        ((ushort*)Cout)[(size_t)gm * 128 + gn] = f2bf(val);
                    else
                        ((float*)Cout)[(size_t)gm * 128 + gn] = val;
                }
            }
        }
    }
}

extern "C" void kernel_launch(void* const* d_in, const int* in_sizes, int n_in,
                              void* d_out, int out_size, void* d_ws, size_t ws_size,
                              hipStream_t stream) {
    const float* features = (const float*)d_in[0];
    const float* pseudo = (const float*)d_in[1];
    const int* src = (const int*)d_in[2];
    const int* dst = (const int*)d_in[3];
    const float* fc_w[3] = {(const float*)d_in[4], (const float*)d_in[10], (const float*)d_in[16]};
    const float* mu[3] = {(const float*)d_in[5], (const float*)d_in[11], (const float*)d_in[17]};
    const float* isg[3] = {(const float*)d_in[6], (const float*)d_in[12], (const float*)d_in[18]};
    const float* bias[3] = {(const float*)d_in[7], (const float*)d_in[13], (const float*)d_in[19]};
    const float* pw[3] = {(const float*)d_in[8], (const float*)d_in[14], (const float*)d_in[20]};
    const float* pb[3] = {(const float*)d_in[9], (const float*)d_in[15], (const float*)d_in[21]};

    char* ws = (char*)d_ws;
    auto alloc = [&](size_t bytes) -> void* {
        void* p = (void*)ws;
        ws += (bytes + 255) & ~(size_t)255;
        return p;
    };
    int* counts = (int*)alloc((size_t)NN * 4);
    int* offsets = (int*)alloc((size_t)(NN + 1) * 4);
    int* cursor = (int*)alloc((size_t)NN * 4);
    int* csr_eidx = (int*)alloc((size_t)NE * 4);
    int* csr_src = (int*)alloc((size_t)NE * 4);
    float* csr_w = (float*)alloc((size_t)3 * NE * 4 * 4);
    int* blockSums = (int*)alloc((size_t)NSB * 4);
    int* blockBase = (int*)alloc((size_t)NSB * 4);
    int* bar = (int*)alloc(256);  // bar[0]=cnt, bar[1]=rel
    ushort* w2t_0 = (ushort*)alloc((size_t)128 * 256 * 2);
    ushort* w2t_1 = (ushort*)alloc((size_t)128 * 512 * 2);
    ushort* w2t_2 = (ushort*)alloc((size_t)128 * 512 * 2);
    ushort* tbuf = (ushort*)alloc((size_t)NN * 512 * 2);
    ushort* h1 = (ushort*)alloc((size_t)NN * 128 * 2);
    ushort* h2 = (ushort*)alloc((size_t)NN * 128 * 2);

    hipMemsetAsync(bar, 0, 8, stream);
    build_csr<<<NB, BT, 0, stream>>>(dst, counts, offsets, cursor, csr_eidx, blockSums,
                                     blockBase, bar + 0, bar + 1);

    EdgeParams P;
    P.pw0 = pw[0]; P.pb0 = pb[0]; P.mu0 = mu[0]; P.is0 = isg[0];
    P.pw1 = pw[1]; P.pb1 = pb[1]; P.mu1 = mu[1]; P.is1 = isg[1];
    P.pw2 = pw[2]; P.pb2 = pb[2]; P.mu2 = mu[2]; P.is2 = isg[2];
    fill2_prep<<<1890, 256, 0, stream>>>(csr_eidx, src, pseudo, P, csr_src, csr_w,
                                         fc_w[0], fc_w[1], fc_w[2], w2t_0, w2t_1, w2t_2);

    const int GB = (NN + 63) / 64;  // 313

    // layer 0: din=64, KD=256
    agg_f32_64<<<NN, 64, 0, stream>>>(features, offsets, csr_src, csr_w + (size_t)0 * NE * 4, tbuf);
    mfma_gemm<256, true><<<GB, 128, 0, stream>>>(tbuf, w2t_0, bias[0], h1, NN);
    // layer 1: din=128, KD=512
    agg_bf_128<<<NN, 64, 0, stream>>>(h1, offsets, csr_src, csr_w + (size_t)1 * NE * 4, tbuf);
    mfma_gemm<512, true><<<GB, 128, 0, stream>>>(tbuf, w2t_1, bias[1], h2, NN);
    // layer 2: din=128, KD=512
    agg_bf_128<<<NN, 64, 0, stream>>>(h2, offsets, csr_src, csr_w + (size_t)2 * NE * 4, tbuf);
    mfma_gemm<512, false><<<GB, 128, 0, stream>>>(tbuf, w2t_2, bias[2], (float*)d_out, NN);
}

// Round 6
// 303.530 us; speedup vs baseline: 1.1007x; 1.1007x over previous
//
#include <hip/hip_runtime.h>
#include <hip/hip_bf16.h>
#include <math.h>

#define NN 20000
#define NE 320000

typedef __attribute__((ext_vector_type(8))) short bf16x8;
typedef __attribute__((ext_vector_type(4))) float f32x4;

__device__ inline float bf2f_lo(uint v) {
    union { uint i; float f; } c; c.i = v << 16; return c.f;
}
__device__ inline float bf2f_hi(uint v) {
    union { uint i; float f; } c; c.i = v & 0xffff0000u; return c.f;
}
__device__ inline ushort f2bf(float f) {
    __hip_bfloat16 h = __float2bfloat16(f);
    return *reinterpret_cast<ushort*>(&h);
}

// ---------------- CSR build ----------------
__global__ void count_kernel(const int* __restrict__ dst, int* __restrict__ counts) {
    int e = blockIdx.x * blockDim.x + threadIdx.x;
    if (e < NE) atomicAdd(&counts[dst[e]], 1);
}

__global__ __launch_bounds__(1024) void scan_kernel(const int* __restrict__ counts,
                                                    int* __restrict__ offsets,
                                                    int* __restrict__ cursor) {
    __shared__ int part[1024];
    const int T = 1024, CH = (NN + T - 1) / T;  // 20
    int t = threadIdx.x;
    int begin = t * CH;
    int end = begin + CH < NN ? begin + CH : NN;
    int s = 0;
    for (int i = begin; i < end; ++i) s += counts[i];
    part[t] = s;
    __syncthreads();
    for (int off = 1; off < T; off <<= 1) {
        int v = (t >= off) ? part[t - off] : 0;
        __syncthreads();
        part[t] += v;
        __syncthreads();
    }
    int run = (t == 0) ? 0 : part[t - 1];
    for (int i = begin; i < end; ++i) {
        offsets[i] = run;
        cursor[i] = run;
        run += counts[i];
    }
    if (t == T - 1) offsets[NN] = part[T - 1];
}

// pass 1: scatter ONLY the 4-byte edge index into CSR position order
__global__ void fill1_kernel(const int* __restrict__ dst, int* __restrict__ cursor,
                             int* __restrict__ csr_eidx) {
    int e = blockIdx.x * blockDim.x + threadIdx.x;
    if (e >= NE) return;
    int pos = atomicAdd(&cursor[dst[e]], 1);
    csr_eidx[pos] = e;
}

struct EdgeParams {
    const float *pw0, *pb0, *mu0, *is0;
    const float *pw1, *pb1, *mu1, *is1;
    const float *pw2, *pb2, *mu2, *is2;
};

__device__ inline float fast_tanh(float x) {
    x = fminf(fmaxf(x, -9.f), 9.f);
    float e = __expf(2.f * x);
    return 1.f - 2.f / (e + 1.f);
}

__device__ inline void layer_w(float p0, float p1, const float* pw, const float* pb,
                               const float* mu, const float* is, float* out4) {
    float u0 = fast_tanh(p0 * pw[0] + p1 * pw[2] + pb[0]);
    float u1 = fast_tanh(p0 * pw[1] + p1 * pw[3] + pb[1]);
#pragma unroll
    for (int k = 0; k < 4; ++k) {
        float d0 = (u0 - mu[k * 2 + 0]) * is[k * 2 + 0];
        float d1 = (u1 - mu[k * 2 + 1]) * is[k * 2 + 1];
        out4[k] = __expf(-0.5f * (d0 * d0 + d1 * d1));
    }
}

// -------- fused: fill2 (blocks 0..1249) + weight transpose (blocks 1250..1889) --------
__global__ void fill2_prep(const int* __restrict__ csr_eidx, const int* __restrict__ src,
                           const float* __restrict__ pseudo, EdgeParams P,
                           int* __restrict__ csr_src, float* __restrict__ csr_w,
                           const float* __restrict__ f0, const float* __restrict__ f1,
                           const float* __restrict__ f2, ushort* __restrict__ w0,
                           ushort* __restrict__ w1, ushort* __restrict__ w2) {
    int bid = blockIdx.x;
    if (bid < 1250) {
        int i = bid * 256 + threadIdx.x;  // 1250*256 == NE exactly
        int e = csr_eidx[i];
        float2 p = *(const float2*)(pseudo + (size_t)e * 2);
        csr_src[i] = src[e];
        float w[4];
        layer_w(p.x, p.y, P.pw0, P.pb0, P.mu0, P.is0, w);
        *(float4*)(csr_w + (size_t)(0 * NE + i) * 4) = make_float4(w[0], w[1], w[2], w[3]);
        layer_w(p.x, p.y, P.pw1, P.pb1, P.mu1, P.is1, w);
        *(float4*)(csr_w + (size_t)(1 * NE + i) * 4) = make_float4(w[0], w[1], w[2], w[3]);
        layer_w(p.x, p.y, P.pw2, P.pb2, P.mu2, P.is2, w);
        *(float4*)(csr_w + (size_t)(2 * NE + i) * 4) = make_float4(w[0], w[1], w[2], w[3]);
    } else {
        int idx = (bid - 1250) * 256 + threadIdx.x;  // 640 blocks cover 163840 exactly
        const float* srcp;
        ushort* dstp;
        int din, KD, li;
        if (idx < 128 * 256) {
            srcp = f0; dstp = w0; din = 64; KD = 256; li = idx;
        } else if (idx < 128 * 256 + 128 * 512) {
            srcp = f1; dstp = w1; din = 128; KD = 512; li = idx - 128 * 256;
        } else {
            srcp = f2; dstp = w2; din = 128; KD = 512; li = idx - 128 * 256 - 128 * 512;
        }
        int n = li / KD;
        int r = li - n * KD;
        int k = r / din;
        int d = r - k * din;
        dstp[li] = f2bf(srcp[d * 512 + k * 128 + n]);
    }
}

// ---------------- layer-0 aggregation (fp32 features) -> bf16 t[n][k*64+d] ----------------
// 256-thread blocks, 4 nodes per block (one wave each); 8-edge unroll for MLP.
__global__ __launch_bounds__(256) void agg_f32_64(const float* __restrict__ h,
                                                  const int* __restrict__ offsets,
                                                  const int* __restrict__ csr_src,
                                                  const float* __restrict__ csr_w,
                                                  ushort* __restrict__ t) {
    int wv = threadIdx.x >> 6, lane = threadIdx.x & 63;
    int n = blockIdx.x * 4 + wv;
    int b = offsets[n], eN = offsets[n + 1];
    float acc[4] = {0.f, 0.f, 0.f, 0.f};
    int i = b;
    for (; i + 8 <= eN; i += 8) {
        int s[8];
        float4 w[8];
        float hv[8];
#pragma unroll
        for (int u = 0; u < 8; ++u) s[u] = csr_src[i + u];
#pragma unroll
        for (int u = 0; u < 8; ++u) w[u] = *(const float4*)(csr_w + (size_t)(i + u) * 4);
#pragma unroll
        for (int u = 0; u < 8; ++u) hv[u] = h[(size_t)s[u] * 64 + lane];
#pragma unroll
        for (int u = 0; u < 8; ++u) {
            acc[0] += w[u].x * hv[u];
            acc[1] += w[u].y * hv[u];
            acc[2] += w[u].z * hv[u];
            acc[3] += w[u].w * hv[u];
        }
    }
    for (; i < eN; ++i) {
        int s0 = csr_src[i];
        float4 w0 = *(const float4*)(csr_w + (size_t)i * 4);
        float hv0 = h[(size_t)s0 * 64 + lane];
        acc[0] += w0.x * hv0;
        acc[1] += w0.y * hv0;
        acc[2] += w0.z * hv0;
        acc[3] += w0.w * hv0;
    }
#pragma unroll
    for (int k = 0; k < 4; ++k) t[(size_t)n * 256 + k * 64 + lane] = f2bf(acc[k]);
}

// ---------------- layer-1/2 aggregation (bf16 h) -> bf16 t; 4 nodes/block, 8-edge unroll ----
__global__ __launch_bounds__(256) void agg_bf_128(const ushort* __restrict__ h,
                                                  const int* __restrict__ offsets,
                                                  const int* __restrict__ csr_src,
                                                  const float* __restrict__ csr_w,
                                                  ushort* __restrict__ t) {
    int wv = threadIdx.x >> 6, lane = threadIdx.x & 63;
    int n = blockIdx.x * 4 + wv;
    int b = offsets[n], eN = offsets[n + 1];
    float acc0 = 0.f, acc1 = 0.f, acc2 = 0.f, acc3 = 0.f;
    float acc4 = 0.f, acc5 = 0.f, acc6 = 0.f, acc7 = 0.f;
    int i = b;
    for (; i + 8 <= eN; i += 8) {
        int s[8];
        float4 w[8];
        uint v[8];
#pragma unroll
        for (int u = 0; u < 8; ++u) s[u] = csr_src[i + u];
#pragma unroll
        for (int u = 0; u < 8; ++u) w[u] = *(const float4*)(csr_w + (size_t)(i + u) * 4);
#pragma unroll
        for (int u = 0; u < 8; ++u) v[u] = *(const uint*)(h + (size_t)s[u] * 128 + lane * 2);
#pragma unroll
        for (int u = 0; u < 8; ++u) {
            float lo = bf2f_lo(v[u]), hi = bf2f_hi(v[u]);
            acc0 += w[u].x * lo; acc1 += w[u].x * hi;
            acc2 += w[u].y * lo; acc3 += w[u].y * hi;
            acc4 += w[u].z * lo; acc5 += w[u].z * hi;
            acc6 += w[u].w * lo; acc7 += w[u].w * hi;
        }
    }
    for (; i < eN; ++i) {
        int s0 = csr_src[i];
        float4 w0 = *(const float4*)(csr_w + (size_t)i * 4);
        uint v0 = *(const uint*)(h + (size_t)s0 * 128 + lane * 2);
        float lo = bf2f_lo(v0), hi = bf2f_hi(v0);
        acc0 += w0.x * lo; acc1 += w0.x * hi;
        acc2 += w0.y * lo; acc3 += w0.y * hi;
        acc4 += w0.z * lo; acc5 += w0.z * hi;
        acc6 += w0.w * lo; acc7 += w0.w * hi;
    }
    ushort2 p;
    p.x = f2bf(acc0); p.y = f2bf(acc1);
    *(ushort2*)(t + (size_t)n * 512 + 0 * 128 + lane * 2) = p;
    p.x = f2bf(acc2); p.y = f2bf(acc3);
    *(ushort2*)(t + (size_t)n * 512 + 1 * 128 + lane * 2) = p;
    p.x = f2bf(acc4); p.y = f2bf(acc5);
    *(ushort2*)(t + (size_t)n * 512 + 2 * 128 + lane * 2) = p;
    p.x = f2bf(acc6); p.y = f2bf(acc7);
    *(ushort2*)(t + (size_t)n * 512 + 3 * 128 + lane * 2) = p;
}

// ---------------- bf16 MFMA GEMM: C[M][128] = A[M][KD] @ Bt[128][KD]^T + bias ----------------
template <int KD, bool OUTBF>
__global__ __launch_bounds__(128) void mfma_gemm(const ushort* __restrict__ A,
                                                 const ushort* __restrict__ Bt,
                                                 const float* __restrict__ bias,
                                                 void* __restrict__ Cout, int M) {
    constexpr int PITCH = 40;  // 32 + 8 ushorts: 80 B rows, 16B-aligned, 2-way banks only
    __shared__ __align__(16) ushort As[64 * PITCH];
    __shared__ __align__(16) ushort Bs[128 * PITCH];
    int tid = threadIdx.x;
    int wave = tid >> 6, lane = tid & 63;
    int quad = lane >> 4, l16 = lane & 15;
    int m0 = blockIdx.x * 64;

    f32x4 acc[4][4];
#pragma unroll
    for (int r = 0; r < 4; ++r)
#pragma unroll
        for (int c = 0; c < 4; ++c) acc[r][c] = (f32x4){0.f, 0.f, 0.f, 0.f};

    for (int k0 = 0; k0 < KD; k0 += 32) {
#pragma unroll
        for (int it = 0; it < 2; ++it) {
            int chunk = it * 128 + tid;
            int row = chunk >> 2, off = chunk & 3;
            int gm = m0 + row;
            uint4 v = make_uint4(0u, 0u, 0u, 0u);
            if (gm < M) v = *(const uint4*)(A + (size_t)gm * KD + k0 + off * 8);
            *(uint4*)(As + row * PITCH + off * 8) = v;
        }
#pragma unroll
        for (int it = 0; it < 4; ++it) {
            int chunk = it * 128 + tid;
            int nr = chunk >> 2, off = chunk & 3;
            uint4 v = *(const uint4*)(Bt + (size_t)nr * KD + k0 + off * 8);
            *(uint4*)(Bs + nr * PITCH + off * 8) = v;
        }
        __syncthreads();

        bf16x8 afrag[4], bfrag[4];
#pragma unroll
        for (int r = 0; r < 4; ++r)
            afrag[r] = *(const bf16x8*)(As + (r * 16 + l16) * PITCH + quad * 8);
#pragma unroll
        for (int c = 0; c < 4; ++c)
            bfrag[c] = *(const bf16x8*)(Bs + (wave * 64 + c * 16 + l16) * PITCH + quad * 8);
#pragma unroll
        for (int r = 0; r < 4; ++r)
#pragma unroll
            for (int c = 0; c < 4; ++c)
                acc[r][c] = __builtin_amdgcn_mfma_f32_16x16x32_bf16(afrag[r], bfrag[c],
                                                                    acc[r][c], 0, 0, 0);
        __syncthreads();
    }

#pragma unroll
    for (int c = 0; c < 4; ++c) {
        int gn = wave * 64 + c * 16 + l16;
        float bv = bias[gn];
#pragma unroll
        for (int r = 0; r < 4; ++r) {
            int gmb = m0 + r * 16 + quad * 4;
#pragma unroll
            for (int i = 0; i < 4; ++i) {
                int gm = gmb + i;
                if (gm < M) {
                    float val = acc[r][c][i] + bv;
                    if (OUTBF)
                        ((ushort*)Cout)[(size_t)gm * 128 + gn] = f2bf(val);
                    else
                        ((float*)Cout)[(size_t)gm * 128 + gn] = val;
                }
            }
        }
    }
}

extern "C" void kernel_launch(void* const* d_in, const int* in_sizes, int n_in,
                              void* d_out, int out_size, void* d_ws, size_t ws_size,
                              hipStream_t stream) {
    const float* features = (const float*)d_in[0];
    const float* pseudo = (const float*)d_in[1];
    const int* src = (const int*)d_in[2];
    const int* dst = (const int*)d_in[3];
    const float* fc_w[3] = {(const float*)d_in[4], (const float*)d_in[10], (const float*)d_in[16]};
    const float* mu[3] = {(const float*)d_in[5], (const float*)d_in[11], (const float*)d_in[17]};
    const float* isg[3] = {(const float*)d_in[6], (const float*)d_in[12], (const float*)d_in[18]};
    const float* bias[3] = {(const float*)d_in[7], (const float*)d_in[13], (const float*)d_in[19]};
    const float* pw[3] = {(const float*)d_in[8], (const float*)d_in[14], (const float*)d_in[20]};
    const float* pb[3] = {(const float*)d_in[9], (const float*)d_in[15], (const float*)d_in[21]};

    char* ws = (char*)d_ws;
    auto alloc = [&](size_t bytes) -> void* {
        void* p = (void*)ws;
        ws += (bytes + 255) & ~(size_t)255;
        return p;
    };
    int* counts = (int*)alloc((size_t)NN * 4);
    int* offsets = (int*)alloc((size_t)(NN + 1) * 4);
    int* cursor = (int*)alloc((size_t)NN * 4);
    int* csr_eidx = (int*)alloc((size_t)NE * 4);
    int* csr_src = (int*)alloc((size_t)NE * 4);
    float* csr_w = (float*)alloc((size_t)3 * NE * 4 * 4);
    ushort* w2t_0 = (ushort*)alloc((size_t)128 * 256 * 2);
    ushort* w2t_1 = (ushort*)alloc((size_t)128 * 512 * 2);
    ushort* w2t_2 = (ushort*)alloc((size_t)128 * 512 * 2);
    ushort* tbuf = (ushort*)alloc((size_t)NN * 512 * 2);
    ushort* h1 = (ushort*)alloc((size_t)NN * 128 * 2);
    ushort* h2 = (ushort*)alloc((size_t)NN * 128 * 2);

    hipMemsetAsync(counts, 0, (size_t)NN * 4, stream);
    count_kernel<<<(NE + 255) / 256, 256, 0, stream>>>(dst, counts);
    scan_kernel<<<1, 1024, 0, stream>>>(counts, offsets, cursor);
    fill1_kernel<<<(NE + 255) / 256, 256, 0, stream>>>(dst, cursor, csr_eidx);

    EdgeParams P;
    P.pw0 = pw[0]; P.pb0 = pb[0]; P.mu0 = mu[0]; P.is0 = isg[0];
    P.pw1 = pw[1]; P.pb1 = pb[1]; P.mu1 = mu[1]; P.is1 = isg[1];
    P.pw2 = pw[2]; P.pb2 = pb[2]; P.mu2 = mu[2]; P.is2 = isg[2];
    fill2_prep<<<1890, 256, 0, stream>>>(csr_eidx, src, pseudo, P, csr_src, csr_w,
                                         fc_w[0], fc_w[1], fc_w[2], w2t_0, w2t_1, w2t_2);

    const int GB = (NN + 63) / 64;  // 313

    // layer 0: din=64, KD=256
    agg_f32_64<<<5000, 256, 0, stream>>>(features, offsets, csr_src, csr_w + (size_t)0 * NE * 4,
                                         tbuf);
    mfma_gemm<256, true><<<GB, 128, 0, stream>>>(tbuf, w2t_0, bias[0], h1, NN);
    // layer 1: din=128, KD=512
    agg_bf_128<<<5000, 256, 0, stream>>>(h1, offsets, csr_src, csr_w + (size_t)1 * NE * 4, tbuf);
    mfma_gemm<512, true><<<GB, 128, 0, stream>>>(tbuf, w2t_1, bias[1], h2, NN);
    // layer 2: din=128, KD=512
    agg_bf_128<<<5000, 256, 0, stream>>>(h2, offsets, csr_src, csr_w + (size_t)2 * NE * 4, tbuf);
    mfma_gemm<512, false><<<GB, 128, 0, stream>>>(tbuf, w2t_2, bias[2], (float*)d_out, NN);
}

// Round 7
// 286.709 us; speedup vs baseline: 1.1652x; 1.0587x over previous
//
#include <hip/hip_runtime.h>
#include <hip/hip_bf16.h>
#include <math.h>

#define NN 20000
#define NE 320000

typedef __attribute__((ext_vector_type(8))) short bf16x8;
typedef __attribute__((ext_vector_type(4))) float f32x4;

__device__ inline float bf2f_lo(uint v) {
    union { uint i; float f; } c; c.i = v << 16; return c.f;
}
__device__ inline float bf2f_hi(uint v) {
    union { uint i; float f; } c; c.i = v & 0xffff0000u; return c.f;
}
__device__ inline ushort f2bf(float f) {
    __hip_bfloat16 h = __float2bfloat16(f);
    return *reinterpret_cast<ushort*>(&h);
}

// ---------------- CSR build ----------------
__global__ void count_kernel(const int* __restrict__ dst, int* __restrict__ counts) {
    int e = blockIdx.x * blockDim.x + threadIdx.x;
    if (e < NE) atomicAdd(&counts[dst[e]], 1);
}

__global__ __launch_bounds__(1024) void scan_kernel(const int* __restrict__ counts,
                                                    int* __restrict__ offsets,
                                                    int* __restrict__ cursor) {
    __shared__ int part[1024];
    const int T = 1024, CH = (NN + T - 1) / T;  // 20
    int t = threadIdx.x;
    int begin = t * CH;
    int end = begin + CH < NN ? begin + CH : NN;
    int s = 0;
    for (int i = begin; i < end; ++i) s += counts[i];
    part[t] = s;
    __syncthreads();
    for (int off = 1; off < T; off <<= 1) {
        int v = (t >= off) ? part[t - off] : 0;
        __syncthreads();
        part[t] += v;
        __syncthreads();
    }
    int run = (t == 0) ? 0 : part[t - 1];
    for (int i = begin; i < end; ++i) {
        offsets[i] = run;
        cursor[i] = run;
        run += counts[i];
    }
    if (t == T - 1) offsets[NN] = part[T - 1];
}

// pass 1: scatter ONLY the 4-byte edge index into CSR position order
__global__ void fill1_kernel(const int* __restrict__ dst, int* __restrict__ cursor,
                             int* __restrict__ csr_eidx) {
    int e = blockIdx.x * blockDim.x + threadIdx.x;
    if (e >= NE) return;
    int pos = atomicAdd(&cursor[dst[e]], 1);
    csr_eidx[pos] = e;
}

struct EdgeParams {
    const float *pw0, *pb0, *mu0, *is0;
    const float *pw1, *pb1, *mu1, *is1;
    const float *pw2, *pb2, *mu2, *is2;
};

__device__ inline float fast_tanh(float x) {
    x = fminf(fmaxf(x, -9.f), 9.f);
    float e = __expf(2.f * x);
    return 1.f - 2.f / (e + 1.f);
}

__device__ inline void layer_w(float p0, float p1, const float* pw, const float* pb,
                               const float* mu, const float* is, float* out4) {
    float u0 = fast_tanh(p0 * pw[0] + p1 * pw[2] + pb[0]);
    float u1 = fast_tanh(p0 * pw[1] + p1 * pw[3] + pb[1]);
#pragma unroll
    for (int k = 0; k < 4; ++k) {
        float d0 = (u0 - mu[k * 2 + 0]) * is[k * 2 + 0];
        float d1 = (u1 - mu[k * 2 + 1]) * is[k * 2 + 1];
        out4[k] = __expf(-0.5f * (d0 * d0 + d1 * d1));
    }
}

// -------- fused: fill2 (blocks 0..1249) + weight transpose (blocks 1250..1889) --------
__global__ void fill2_prep(const int* __restrict__ csr_eidx, const int* __restrict__ src,
                           const float* __restrict__ pseudo, EdgeParams P,
                           int* __restrict__ csr_src, float* __restrict__ csr_w,
                           const float* __restrict__ f0, const float* __restrict__ f1,
                           const float* __restrict__ f2, ushort* __restrict__ w0,
                           ushort* __restrict__ w1, ushort* __restrict__ w2) {
    int bid = blockIdx.x;
    if (bid < 1250) {
        int i = bid * 256 + threadIdx.x;  // 1250*256 == NE exactly
        int e = csr_eidx[i];
        float2 p = *(const float2*)(pseudo + (size_t)e * 2);
        csr_src[i] = src[e];
        float w[4];
        layer_w(p.x, p.y, P.pw0, P.pb0, P.mu0, P.is0, w);
        *(float4*)(csr_w + (size_t)(0 * NE + i) * 4) = make_float4(w[0], w[1], w[2], w[3]);
        layer_w(p.x, p.y, P.pw1, P.pb1, P.mu1, P.is1, w);
        *(float4*)(csr_w + (size_t)(1 * NE + i) * 4) = make_float4(w[0], w[1], w[2], w[3]);
        layer_w(p.x, p.y, P.pw2, P.pb2, P.mu2, P.is2, w);
        *(float4*)(csr_w + (size_t)(2 * NE + i) * 4) = make_float4(w[0], w[1], w[2], w[3]);
    } else {
        int idx = (bid - 1250) * 256 + threadIdx.x;  // 640 blocks cover 163840 exactly
        const float* srcp;
        ushort* dstp;
        int din, KD, li;
        if (idx < 128 * 256) {
            srcp = f0; dstp = w0; din = 64; KD = 256; li = idx;
        } else if (idx < 128 * 256 + 128 * 512) {
            srcp = f1; dstp = w1; din = 128; KD = 512; li = idx - 128 * 256;
        } else {
            srcp = f2; dstp = w2; din = 128; KD = 512; li = idx - 128 * 256 - 128 * 512;
        }
        int n = li / KD;
        int r = li - n * KD;
        int k = r / din;
        int d = r - k * din;
        dstp[li] = f2bf(srcp[d * 512 + k * 128 + n]);
    }
}

// ---------------- fused layer: agg (r4 pattern, LDS t-tile) + MFMA GEMM ----------------
// block = 256 threads (4 waves), 16 nodes; wave w aggs nodes 4w..4w+3, then GEMM cols 32w..32w+31.
template <int DIN, bool INF32, bool OUTBF>
__global__ __launch_bounds__(256) void layer_fused(const void* __restrict__ hin,
                                                   const int* __restrict__ offsets,
                                                   const int* __restrict__ csr_src,
                                                   const float* __restrict__ csr_w,
                                                   const ushort* __restrict__ Bt,
                                                   const float* __restrict__ bias,
                                                   void* __restrict__ hout) {
    constexpr int KD = 4 * DIN;
    constexpr int PITCH = KD + 8;  // ushorts; 16B-aligned rows
    __shared__ __align__(16) ushort Ts[16 * PITCH];
    int wv = threadIdx.x >> 6, lane = threadIdx.x & 63;
    int l16 = lane & 15, quad = lane >> 4;
    int nb = blockIdx.x * 16;

    // ---- aggregation phase ----
#pragma unroll
    for (int j = 0; j < 4; ++j) {
        int row = wv * 4 + j;
        int n = nb + row;
        int b = offsets[n], eN = offsets[n + 1];
        if (INF32) {
            const float* h = (const float*)hin;
            float acc[4] = {0.f, 0.f, 0.f, 0.f};
            int i = b;
            for (; i + 4 <= eN; i += 4) {
                int s0 = csr_src[i], s1 = csr_src[i + 1], s2 = csr_src[i + 2],
                    s3 = csr_src[i + 3];
                float4 w0 = *(const float4*)(csr_w + (size_t)i * 4);
                float4 w1 = *(const float4*)(csr_w + (size_t)(i + 1) * 4);
                float4 w2 = *(const float4*)(csr_w + (size_t)(i + 2) * 4);
                float4 w3 = *(const float4*)(csr_w + (size_t)(i + 3) * 4);
                float hv0 = h[(size_t)s0 * 64 + lane];
                float hv1 = h[(size_t)s1 * 64 + lane];
                float hv2 = h[(size_t)s2 * 64 + lane];
                float hv3 = h[(size_t)s3 * 64 + lane];
                acc[0] += w0.x * hv0 + w1.x * hv1 + w2.x * hv2 + w3.x * hv3;
                acc[1] += w0.y * hv0 + w1.y * hv1 + w2.y * hv2 + w3.y * hv3;
                acc[2] += w0.z * hv0 + w1.z * hv1 + w2.z * hv2 + w3.z * hv3;
                acc[3] += w0.w * hv0 + w1.w * hv1 + w2.w * hv2 + w3.w * hv3;
            }
            for (; i < eN; ++i) {
                int s0 = csr_src[i];
                float4 w0 = *(const float4*)(csr_w + (size_t)i * 4);
                float hv0 = h[(size_t)s0 * 64 + lane];
                acc[0] += w0.x * hv0;
                acc[1] += w0.y * hv0;
                acc[2] += w0.z * hv0;
                acc[3] += w0.w * hv0;
            }
#pragma unroll
            for (int k = 0; k < 4; ++k) Ts[row * PITCH + k * 64 + lane] = f2bf(acc[k]);
        } else {
            const ushort* h = (const ushort*)hin;
            float a00 = 0.f, a01 = 0.f, a10 = 0.f, a11 = 0.f;
            float a20 = 0.f, a21 = 0.f, a30 = 0.f, a31 = 0.f;
            int i = b;
            for (; i + 4 <= eN; i += 4) {
                int s0 = csr_src[i], s1 = csr_src[i + 1], s2 = csr_src[i + 2],
                    s3 = csr_src[i + 3];
                float4 w0 = *(const float4*)(csr_w + (size_t)i * 4);
                float4 w1 = *(const float4*)(csr_w + (size_t)(i + 1) * 4);
                float4 w2 = *(const float4*)(csr_w + (size_t)(i + 2) * 4);
                float4 w3 = *(const float4*)(csr_w + (size_t)(i + 3) * 4);
                uint v0 = *(const uint*)(h + (size_t)s0 * 128 + lane * 2);
                uint v1 = *(const uint*)(h + (size_t)s1 * 128 + lane * 2);
                uint v2 = *(const uint*)(h + (size_t)s2 * 128 + lane * 2);
                uint v3 = *(const uint*)(h + (size_t)s3 * 128 + lane * 2);
                float p0 = bf2f_lo(v0), q0 = bf2f_hi(v0);
                float p1 = bf2f_lo(v1), q1 = bf2f_hi(v1);
                float p2 = bf2f_lo(v2), q2 = bf2f_hi(v2);
                float p3 = bf2f_lo(v3), q3 = bf2f_hi(v3);
                a00 += w0.x * p0 + w1.x * p1 + w2.x * p2 + w3.x * p3;
                a01 += w0.x * q0 + w1.x * q1 + w2.x * q2 + w3.x * q3;
                a10 += w0.y * p0 + w1.y * p1 + w2.y * p2 + w3.y * p3;
                a11 += w0.y * q0 + w1.y * q1 + w2.y * q2 + w3.y * q3;
                a20 += w0.z * p0 + w1.z * p1 + w2.z * p2 + w3.z * p3;
                a21 += w0.z * q0 + w1.z * q1 + w2.z * q2 + w3.z * q3;
                a30 += w0.w * p0 + w1.w * p1 + w2.w * p2 + w3.w * p3;
                a31 += w0.w * q0 + w1.w * q1 + w2.w * q2 + w3.w * q3;
            }
            for (; i < eN; ++i) {
                int s0 = csr_src[i];
                float4 w0 = *(const float4*)(csr_w + (size_t)i * 4);
                uint v0 = *(const uint*)(h + (size_t)s0 * 128 + lane * 2);
                float p0 = bf2f_lo(v0), q0 = bf2f_hi(v0);
                a00 += w0.x * p0; a01 += w0.x * q0;
                a10 += w0.y * p0; a11 += w0.y * q0;
                a20 += w0.z * p0; a21 += w0.z * q0;
                a30 += w0.w * p0; a31 += w0.w * q0;
            }
            ushort2 p;
            p.x = f2bf(a00); p.y = f2bf(a01);
            *(ushort2*)(Ts + row * PITCH + 0 * 128 + lane * 2) = p;
            p.x = f2bf(a10); p.y = f2bf(a11);
            *(ushort2*)(Ts + row * PITCH + 1 * 128 + lane * 2) = p;
            p.x = f2bf(a20); p.y = f2bf(a21);
            *(ushort2*)(Ts + row * PITCH + 2 * 128 + lane * 2) = p;
            p.x = f2bf(a30); p.y = f2bf(a31);
            *(ushort2*)(Ts + row * PITCH + 3 * 128 + lane * 2) = p;
        }
    }
    __syncthreads();

    // ---- GEMM phase: M=16 (tile), wave wv covers cols [32wv, 32wv+32) ----
    f32x4 acc[2];
    acc[0] = (f32x4){0.f, 0.f, 0.f, 0.f};
    acc[1] = (f32x4){0.f, 0.f, 0.f, 0.f};
    for (int k0 = 0; k0 < KD; k0 += 32) {
        bf16x8 af = *(const bf16x8*)(Ts + l16 * PITCH + k0 + quad * 8);
#pragma unroll
        for (int c = 0; c < 2; ++c) {
            int nr = wv * 32 + c * 16 + l16;
            bf16x8 bfr = *(const bf16x8*)(Bt + (size_t)nr * KD + k0 + quad * 8);
            acc[c] = __builtin_amdgcn_mfma_f32_16x16x32_bf16(af, bfr, acc[c], 0, 0, 0);
        }
    }
#pragma unroll
    for (int c = 0; c < 2; ++c) {
        int gn = wv * 32 + c * 16 + l16;
        float bv = bias[gn];
#pragma unroll
        for (int i = 0; i < 4; ++i) {
            int gm = nb + quad * 4 + i;
            float val = acc[c][i] + bv;
            if (OUTBF)
                ((ushort*)hout)[(size_t)gm * 128 + gn] = f2bf(val);
            else
                ((float*)hout)[(size_t)gm * 128 + gn] = val;
        }
    }
}

extern "C" void kernel_launch(void* const* d_in, const int* in_sizes, int n_in,
                              void* d_out, int out_size, void* d_ws, size_t ws_size,
                              hipStream_t stream) {
    const float* features = (const float*)d_in[0];
    const float* pseudo = (const float*)d_in[1];
    const int* src = (const int*)d_in[2];
    const int* dst = (const int*)d_in[3];
    const float* fc_w[3] = {(const float*)d_in[4], (const float*)d_in[10], (const float*)d_in[16]};
    const float* mu[3] = {(const float*)d_in[5], (const float*)d_in[11], (const float*)d_in[17]};
    const float* isg[3] = {(const float*)d_in[6], (const float*)d_in[12], (const float*)d_in[18]};
    const float* bias[3] = {(const float*)d_in[7], (const float*)d_in[13], (const float*)d_in[19]};
    const float* pw[3] = {(const float*)d_in[8], (const float*)d_in[14], (const float*)d_in[20]};
    const float* pb[3] = {(const float*)d_in[9], (const float*)d_in[15], (const float*)d_in[21]};

    char* ws = (char*)d_ws;
    auto alloc = [&](size_t bytes) -> void* {
        void* p = (void*)ws;
        ws += (bytes + 255) & ~(size_t)255;
        return p;
    };
    int* counts = (int*)alloc((size_t)NN * 4);
    int* offsets = (int*)alloc((size_t)(NN + 1) * 4);
    int* cursor = (int*)alloc((size_t)NN * 4);
    int* csr_eidx = (int*)alloc((size_t)NE * 4);
    int* csr_src = (int*)alloc((size_t)NE * 4);
    float* csr_w = (float*)alloc((size_t)3 * NE * 4 * 4);
    ushort* w2t_0 = (ushort*)alloc((size_t)128 * 256 * 2);
    ushort* w2t_1 = (ushort*)alloc((size_t)128 * 512 * 2);
    ushort* w2t_2 = (ushort*)alloc((size_t)128 * 512 * 2);
    ushort* h1 = (ushort*)alloc((size_t)NN * 128 * 2);
    ushort* h2 = (ushort*)alloc((size_t)NN * 128 * 2);

    hipMemsetAsync(counts, 0, (size_t)NN * 4, stream);
    count_kernel<<<(NE + 255) / 256, 256, 0, stream>>>(dst, counts);
    scan_kernel<<<1, 1024, 0, stream>>>(counts, offsets, cursor);
    fill1_kernel<<<(NE + 255) / 256, 256, 0, stream>>>(dst, cursor, csr_eidx);

    EdgeParams P;
    P.pw0 = pw[0]; P.pb0 = pb[0]; P.mu0 = mu[0]; P.is0 = isg[0];
    P.pw1 = pw[1]; P.pb1 = pb[1]; P.mu1 = mu[1]; P.is1 = isg[1];
    P.pw2 = pw[2]; P.pb2 = pb[2]; P.mu2 = mu[2]; P.is2 = isg[2];
    fill2_prep<<<1890, 256, 0, stream>>>(csr_eidx, src, pseudo, P, csr_src, csr_w,
                                         fc_w[0], fc_w[1], fc_w[2], w2t_0, w2t_1, w2t_2);

    const int GB = NN / 16;  // 1250

    layer_fused<64, true, true><<<GB, 256, 0, stream>>>(
        features, offsets, csr_src, csr_w + (size_t)0 * NE * 4, w2t_0, bias[0], h1);
    layer_fused<128, false, true><<<GB, 256, 0, stream>>>(
        h1, offsets, csr_src, csr_w + (size_t)1 * NE * 4, w2t_1, bias[1], h2);
    layer_fused<128, false, false><<<GB, 256, 0, stream>>>(
        h2, offsets, csr_src, csr_w + (size_t)2 * NE * 4, w2t_2, bias[2], (float*)d_out);
}